// Round 1
// baseline (730.603 us; speedup 1.0000x reference)
//
#include <hip/hip_runtime.h>
#include <stdint.h>
#include <stdio.h>

#define BB   16
#define LL   512
#define CC   384
#define FF   384
#define KW   3
#define MEL  4096
#define KKT  (CC*KW)   // 1152

// output section offsets (fp32 elements)
#define O_OUT 0
#define N_OUT (BB*MEL*CC)          // 25165824
#define O_DUR (N_OUT)              // + 16*512
#define O_PIT (O_DUR + BB*LL)      // + 16*4096
#define O_EN  (O_PIT + BB*MEL)

using bf16x8 = __attribute__((ext_vector_type(8))) short;
using f32x4  = __attribute__((ext_vector_type(4))) float;

__device__ __forceinline__ unsigned short f2bf(float v) {
    union { float f; unsigned int u; } cv; cv.f = v;
    unsigned int u = cv.u;
    u += 0x7FFFu + ((u >> 16) & 1u);   // RNE (no NaNs in this workload)
    return (unsigned short)(u >> 16);
}
__device__ __forceinline__ float bf2f(unsigned short u) {
    union { unsigned int u; float f; } cv; cv.u = ((unsigned int)u) << 16; return cv.f;
}

// ---------------- weight transform: w[F][C][K] fp32 -> wt[F][k*C+c] bf16 ----
__global__ void wtrans_kernel(const float* __restrict__ w, unsigned short* __restrict__ wt) {
    int i = blockIdx.x * 256 + threadIdx.x;
    if (i >= FF * KKT) return;
    int f = i / KKT;
    int r = i - f * KKT;
    int k = r / CC;
    int c = r - k * CC;
    wt[i] = f2bf(w[(size_t)f * KKT + c * KW + k]);
}

// ---------------- x fp32 -> padded bf16 [B][L+2][C] ------------------------
__global__ void convert_x_kernel(const float* __restrict__ x, unsigned short* __restrict__ o) {
    int i = blockIdx.x * 256 + threadIdx.x;
    if (i >= BB * LL * CC) return;
    int b = i / (LL * CC);
    int r = i - b * (LL * CC);
    int t = r / CC;
    int c = r - t * CC;
    o[((size_t)b * (LL + 2) + t + 1) * CC + c] = f2bf(x[i]);
}

// ---------------- zero the two pad rows per batch --------------------------
__global__ void zpad_kernel(unsigned short* __restrict__ buf, int T) {
    int b = blockIdx.x >> 1;
    int w = blockIdx.x & 1;
    size_t row = (size_t)b * (T + 2) + (w ? (T + 1) : 0);
    buf[row * CC + threadIdx.x] = 0;
}

// ---------------- conv GEMM: [Bn*T,1152]x[1152,384], +bias, ReLU, bf16 out -
// inb: padded bf16 [BB][T+2][CC]; wt: bf16 [384][1152] (B^T); out: padded bf16
template<int T>
__global__ __launch_bounds__(256)
void conv_gemm_kernel(const unsigned short* __restrict__ inb,
                      const unsigned short* __restrict__ wt,
                      const float* __restrict__ bias,
                      unsigned short* __restrict__ outb) {
    __shared__ __align__(16) unsigned short As[128 * 32];
    __shared__ __align__(16) unsigned short Bs[128 * 32];  // [n][kk]

    const int m0 = blockIdx.x * 128;
    const int n0 = blockIdx.y * 128;
    const int b  = m0 / T;
    const int t0 = m0 - b * T;
    const int tid  = threadIdx.x;
    const int lane = tid & 63;
    const int wv   = tid >> 6;
    const int wr   = wv >> 1;          // wave row (0..1) -> 64 rows
    const int wc   = wv & 1;           // wave col (0..1) -> 64 cols
    const int sr   = tid >> 2;         // staging row 0..63
    const int sc   = (tid & 3) * 8;    // staging col (bf16 elems)

    f32x4 acc[4][4] = {};

    for (int kk0 = 0; kk0 < KKT; kk0 += 32) {
        const int kseg = kk0 / CC;           // 0..2 (chunks never straddle taps)
        const int c0   = kk0 - kseg * CC;
        #pragma unroll
        for (int j = 0; j < 2; ++j) {
            const int r = j * 64 + sr;
            const unsigned short* ga = inb +
                (((size_t)b * (T + 2) + (t0 + r + kseg)) * CC + c0 + sc);
            *reinterpret_cast<bf16x8*>(&As[r * 32 + sc]) =
                *reinterpret_cast<const bf16x8*>(ga);
            const unsigned short* gb = wt + ((size_t)(n0 + r) * KKT + kk0 + sc);
            *reinterpret_cast<bf16x8*>(&Bs[r * 32 + sc]) =
                *reinterpret_cast<const bf16x8*>(gb);
        }
        __syncthreads();

        bf16x8 af[4], bfr[4];
        #pragma unroll
        for (int i = 0; i < 4; ++i) {
            const int ar = wr * 64 + i * 16 + (lane & 15);
            af[i]  = *reinterpret_cast<bf16x8*>(&As[ar * 32 + (lane >> 4) * 8]);
            const int bn = wc * 64 + i * 16 + (lane & 15);
            bfr[i] = *reinterpret_cast<bf16x8*>(&Bs[bn * 32 + (lane >> 4) * 8]);
        }
        #pragma unroll
        for (int i = 0; i < 4; ++i)
            #pragma unroll
            for (int jn = 0; jn < 4; ++jn)
                acc[i][jn] = __builtin_amdgcn_mfma_f32_16x16x32_bf16(
                    af[i], bfr[jn], acc[i][jn], 0, 0, 0);
        __syncthreads();
    }

    // epilogue: bias + ReLU -> bf16 padded out
    #pragma unroll
    for (int jn = 0; jn < 4; ++jn) {
        const int col = n0 + wc * 64 + jn * 16 + (lane & 15);
        const float bsv = bias[col];
        #pragma unroll
        for (int i = 0; i < 4; ++i) {
            #pragma unroll
            for (int r = 0; r < 4; ++r) {
                const int row = wr * 64 + i * 16 + (lane >> 4) * 4 + r;
                const int t = t0 + row;
                float v = acc[i][jn][r] + bsv;
                v = v > 0.f ? v : 0.f;
                outb[((size_t)b * (T + 2) + (t + 1)) * CC + col] = f2bf(v);
            }
        }
    }
}

// ---------------- LayerNorm over F=384, one wave per row -------------------
template<int T>
__global__ void ln_kernel(const unsigned short* __restrict__ in,
                          const float* __restrict__ g, const float* __restrict__ be,
                          unsigned short* __restrict__ out) {
    const int row = blockIdx.x;
    const int b = row / T, t = row - b * T;
    const unsigned short* p = in  + ((size_t)b * (T + 2) + t + 1) * CC;
    unsigned short*       q = out + ((size_t)b * (T + 2) + t + 1) * CC;
    const int lane = threadIdx.x;
    float v[6], s = 0.f, s2 = 0.f;
    #pragma unroll
    for (int j = 0; j < 6; ++j) {
        float x = bf2f(p[j * 64 + lane]);
        v[j] = x; s += x; s2 += x * x;
    }
    #pragma unroll
    for (int off = 32; off; off >>= 1) {
        s  += __shfl_xor(s,  off);
        s2 += __shfl_xor(s2, off);
    }
    const float mu  = s * (1.f / 384.f);
    const float var = s2 * (1.f / 384.f) - mu * mu;
    const float rs  = rsqrtf(var + 1e-5f);
    #pragma unroll
    for (int j = 0; j < 6; ++j) {
        const int f = j * 64 + lane;
        q[f] = f2bf((v[j] - mu) * rs * g[f] + be[f]);
    }
}

// ---------------- Linear F->1, one wave per row ----------------------------
template<int T>
__global__ void linear_kernel(const unsigned short* __restrict__ in,
                              const float* __restrict__ wl, const float* __restrict__ bl,
                              float* __restrict__ outp) {
    const int row = blockIdx.x;
    const int b = row / T, t = row - b * T;
    const unsigned short* p = in + ((size_t)b * (T + 2) + t + 1) * CC;
    const int lane = threadIdx.x;
    float s = 0.f;
    #pragma unroll
    for (int j = 0; j < 6; ++j) {
        const int f = j * 64 + lane;
        s += bf2f(p[f]) * wl[f];
    }
    #pragma unroll
    for (int off = 32; off; off >>= 1) s += __shfl_xor(s, off);
    if (lane == 0) outp[row] = s + bl[0];
}

// ---------------- cumsum of dur per batch ----------------------------------
__global__ void cumsum_kernel(const int* __restrict__ dur, int* __restrict__ cum) {
    __shared__ int s[LL];
    const int b = blockIdx.x, t = threadIdx.x;
    s[t] = dur[b * LL + t];
    __syncthreads();
    for (int off = 1; off < LL; off <<= 1) {
        int v = (t >= off) ? s[t - off] : 0;
        __syncthreads();
        s[t] += v;
        __syncthreads();
    }
    cum[b * LL + t] = s[t];
}

// ---------------- frame -> phoneme index (binary search), -1 if masked -----
__global__ void idx_kernel(const int* __restrict__ cum, int* __restrict__ idxm) {
    const int i = blockIdx.x * 256 + threadIdx.x;
    if (i >= BB * MEL) return;
    const int b = i / MEL, t = i - b * MEL;
    const int* cb = cum + b * LL;
    const int total = cb[LL - 1];
    int lo = 0, hi = LL;
    while (lo < hi) {
        const int mid = (lo + hi) >> 1;
        if (cb[mid] <= t) lo = mid + 1; else hi = mid;
    }
    int id = lo > LL - 1 ? LL - 1 : lo;
    idxm[i] = (t < total) ? id : -1;
}

// ---------------- gather: expanded fp32 -> d_out, bf16 padded -> bb0 -------
__global__ void gather_kernel(const float* __restrict__ x, const int* __restrict__ idxm,
                              float* __restrict__ out0, unsigned short* __restrict__ bb0) {
    const int row = blockIdx.x;
    const int b = row / MEL, t = row - b * MEL;
    const int f = threadIdx.x;
    const int id = idxm[row];
    const float v = (id >= 0) ? x[((size_t)b * LL + id) * CC + f] : 0.f;
    out0[(size_t)row * CC + f] = v;
    bb0[((size_t)b * (MEL + 2) + t + 1) * CC + f] = f2bf(v);
}

// ---------------- out += scalar(row); also produce bf16 padded copy --------
__global__ void addp_kernel(const float* __restrict__ pv, float* __restrict__ out0,
                            unsigned short* __restrict__ bb0) {
    const int row = blockIdx.x;
    const int b = row / MEL, t = row - b * MEL;
    const int f = threadIdx.x;
    const float pval = pv[row];
    const size_t o = (size_t)row * CC + f;
    const float v = out0[o] + pval;
    out0[o] = v;
    bb0[((size_t)b * (MEL + 2) + t + 1) * CC + f] = f2bf(v);
}

__global__ void adde_kernel(const float* __restrict__ ev, float* __restrict__ out0) {
    const int row = blockIdx.x;
    const int f = threadIdx.x;
    const size_t o = (size_t)row * CC + f;
    out0[o] = out0[o] + ev[row];
}

extern "C" void kernel_launch(void* const* d_in, const int* in_sizes, int n_in,
                              void* d_out, int out_size, void* d_ws, size_t ws_size,
                              hipStream_t stream) {
    const float* x = (const float*)d_in[0];
    // predictor params: base index 1 (dp), 11 (pp), 21 (ep)
    const float* P[30];
    for (int i = 0; i < 30; ++i) P[i] = (const float*)d_in[1 + i];
    const int* dur = (const int*)d_in[31];
    float* out = (float*)d_out;

    char* ws = (char*)d_ws;
    const size_t WTT_ELEMS = (size_t)FF * KKT;            // 442368
    const size_t WTT_BYTES = WTT_ELEMS * 2;               // 884736
    unsigned short* wtt[6];
    for (int i = 0; i < 6; ++i) wtt[i] = (unsigned short*)(ws + i * WTT_BYTES);
    int* cum  = (int*)(ws + 5308416);
    int* idxm = (int*)(ws + 5341184);
    unsigned short* sb0 = (unsigned short*)(ws + 5603328);
    unsigned short* sb1 = sb0 + (size_t)BB * (LL + 2) * CC;
    unsigned short* sb2 = sb1 + (size_t)BB * (LL + 2) * CC;
    unsigned short* bb0 = (unsigned short*)(ws + 24551424);
    unsigned short* bb1 = bb0 + (size_t)BB * (MEL + 2) * CC;
    unsigned short* bb2 = bb1 + (size_t)BB * (MEL + 2) * CC;
    const size_t need = 24551424 + 3 * (size_t)BB * (MEL + 2) * CC * 2;
    if (ws_size < need)
        fprintf(stderr, "kernel_launch: ws too small: %zu < %zu\n", ws_size, need);

    const float *dp_w1=P[0], *dp_b1=P[1], *dp_g1=P[2], *dp_be1=P[3], *dp_w2=P[4],
                *dp_b2=P[5], *dp_g2=P[6], *dp_be2=P[7], *dp_wl=P[8], *dp_bl=P[9];
    const float *pp_w1=P[10], *pp_b1=P[11], *pp_g1=P[12], *pp_be1=P[13], *pp_w2=P[14],
                *pp_b2=P[15], *pp_g2=P[16], *pp_be2=P[17], *pp_wl=P[18], *pp_bl=P[19];
    const float *ep_w1=P[20], *ep_b1=P[21], *ep_g1=P[22], *ep_be1=P[23], *ep_w2=P[24],
                *ep_b2=P[25], *ep_g2=P[26], *ep_be2=P[27], *ep_wl=P[28], *ep_bl=P[29];

    const int wtg = (int)((WTT_ELEMS + 255) / 256);
    wtrans_kernel<<<wtg, 256, 0, stream>>>(dp_w1, wtt[0]);
    wtrans_kernel<<<wtg, 256, 0, stream>>>(dp_w2, wtt[1]);
    wtrans_kernel<<<wtg, 256, 0, stream>>>(pp_w1, wtt[2]);
    wtrans_kernel<<<wtg, 256, 0, stream>>>(pp_w2, wtt[3]);
    wtrans_kernel<<<wtg, 256, 0, stream>>>(ep_w1, wtt[4]);
    wtrans_kernel<<<wtg, 256, 0, stream>>>(ep_w2, wtt[5]);

    convert_x_kernel<<<(BB * LL * CC + 255) / 256, 256, 0, stream>>>(x, sb0);
    zpad_kernel<<<BB * 2, CC, 0, stream>>>(sb0, LL);
    zpad_kernel<<<BB * 2, CC, 0, stream>>>(sb1, LL);
    zpad_kernel<<<BB * 2, CC, 0, stream>>>(sb2, LL);

    // duration predictor (T=512)
    {
        dim3 g(BB * LL / 128, 3);
        conv_gemm_kernel<LL><<<g, 256, 0, stream>>>(sb0, wtt[0], dp_b1, sb1);
        ln_kernel<LL><<<BB * LL, 64, 0, stream>>>(sb1, dp_g1, dp_be1, sb2);
        conv_gemm_kernel<LL><<<g, 256, 0, stream>>>(sb2, wtt[1], dp_b2, sb1);
        ln_kernel<LL><<<BB * LL, 64, 0, stream>>>(sb1, dp_g2, dp_be2, sb2);
        linear_kernel<LL><<<BB * LL, 64, 0, stream>>>(sb2, dp_wl, dp_bl, out + O_DUR);
    }

    // length regulate
    cumsum_kernel<<<BB, LL, 0, stream>>>(dur, cum);
    idx_kernel<<<(BB * MEL + 255) / 256, 256, 0, stream>>>(cum, idxm);
    zpad_kernel<<<BB * 2, CC, 0, stream>>>(bb0, MEL);
    zpad_kernel<<<BB * 2, CC, 0, stream>>>(bb1, MEL);
    zpad_kernel<<<BB * 2, CC, 0, stream>>>(bb2, MEL);
    gather_kernel<<<BB * MEL, CC, 0, stream>>>(x, idxm, out + O_OUT, bb0);

    // pitch predictor (T=4096) on expanded
    {
        dim3 g(BB * MEL / 128, 3);
        conv_gemm_kernel<MEL><<<g, 256, 0, stream>>>(bb0, wtt[2], pp_b1, bb1);
        ln_kernel<MEL><<<BB * MEL, 64, 0, stream>>>(bb1, pp_g1, pp_be1, bb2);
        conv_gemm_kernel<MEL><<<g, 256, 0, stream>>>(bb2, wtt[3], pp_b2, bb1);
        ln_kernel<MEL><<<BB * MEL, 64, 0, stream>>>(bb1, pp_g2, pp_be2, bb2);
        linear_kernel<MEL><<<BB * MEL, 64, 0, stream>>>(bb2, pp_wl, pp_bl, out + O_PIT);
    }

    // out = expanded + pitches (and bf16 copy for energy predictor)
    addp_kernel<<<BB * MEL, CC, 0, stream>>>(out + O_PIT, out + O_OUT, bb0);

    // energy predictor (T=4096) on out
    {
        dim3 g(BB * MEL / 128, 3);
        conv_gemm_kernel<MEL><<<g, 256, 0, stream>>>(bb0, wtt[4], ep_b1, bb1);
        ln_kernel<MEL><<<BB * MEL, 64, 0, stream>>>(bb1, ep_g1, ep_be1, bb2);
        conv_gemm_kernel<MEL><<<g, 256, 0, stream>>>(bb2, wtt[5], ep_b2, bb1);
        ln_kernel<MEL><<<BB * MEL, 64, 0, stream>>>(bb1, ep_g2, ep_be2, bb2);
        linear_kernel<MEL><<<BB * MEL, 64, 0, stream>>>(bb2, ep_wl, ep_bl, out + O_EN);
    }

    // out += energies
    adde_kernel<<<BB * MEL, CC, 0, stream>>>(out + O_EN, out + O_OUT);
}

// Round 2
// 644.711 us; speedup vs baseline: 1.1332x; 1.1332x over previous
//
#include <hip/hip_runtime.h>
#include <stdint.h>
#include <stdio.h>

#define BB   16
#define LL   512
#define CC   384
#define FF   384
#define KW   3
#define MEL  4096
#define KKT  (CC*KW)   // 1152

// output section offsets (fp32 elements)
#define O_OUT 0
#define N_OUT (BB*MEL*CC)          // 25165824
#define O_DUR (N_OUT)              // + 16*512
#define O_PIT (O_DUR + BB*LL)      // + 16*4096
#define O_EN  (O_PIT + BB*MEL)

using bf16x8 = __attribute__((ext_vector_type(8))) short;
using f32x4  = __attribute__((ext_vector_type(4))) float;

__device__ __forceinline__ unsigned short f2bf(float v) {
    union { float f; unsigned int u; } cv; cv.f = v;
    unsigned int u = cv.u;
    u += 0x7FFFu + ((u >> 16) & 1u);   // RNE (no NaNs in this workload)
    return (unsigned short)(u >> 16);
}
__device__ __forceinline__ float bf2f(unsigned short u) {
    union { unsigned int u; float f; } cv; cv.u = ((unsigned int)u) << 16; return cv.f;
}

__device__ __forceinline__ void gld_lds16(const unsigned short* gp, unsigned short* lp) {
    __builtin_amdgcn_global_load_lds(
        (const __attribute__((address_space(1))) unsigned int*)gp,
        (__attribute__((address_space(3))) unsigned int*)lp, 16, 0, 0);
}

// ---------------- weight transform: w[F][C][K] fp32 -> wt[F][k*C+c] bf16 ----
__global__ void wtrans_kernel(const float* __restrict__ w, unsigned short* __restrict__ wt) {
    int i = blockIdx.x * 256 + threadIdx.x;
    if (i >= FF * KKT) return;
    int f = i / KKT;
    int r = i - f * KKT;
    int k = r / CC;
    int c = r - k * CC;
    wt[i] = f2bf(w[(size_t)f * KKT + c * KW + k]);
}

// ---------------- x fp32 -> padded bf16 [B][L+2][C] ------------------------
__global__ void convert_x_kernel(const float* __restrict__ x, unsigned short* __restrict__ o) {
    int i = blockIdx.x * 256 + threadIdx.x;
    if (i >= BB * LL * CC) return;
    int b = i / (LL * CC);
    int r = i - b * (LL * CC);
    int t = r / CC;
    int c = r - t * CC;
    o[((size_t)b * (LL + 2) + t + 1) * CC + c] = f2bf(x[i]);
}

// ---------------- zero the two pad rows per batch --------------------------
__global__ void zpad_kernel(unsigned short* __restrict__ buf, int T) {
    int b = blockIdx.x >> 1;
    int w = blockIdx.x & 1;
    size_t row = (size_t)b * (T + 2) + (w ? (T + 1) : 0);
    buf[row * CC + threadIdx.x] = 0;
}

// ---------------- conv GEMM: [B*T,1152]x[1152,384], +bias, ReLU, bf16 out --
// global_load_lds staging (linear LDS dest) with pre-swizzled global source;
// ds_read applies the same XOR: chunk' = chunk ^ ((row ^ row>>2) & 3).
// Bijective XCD swizzle, n-fastest so each XCD reuses its A-panels in L2.
template<int T>
__global__ __launch_bounds__(256)
void conv_gemm_kernel(const unsigned short* __restrict__ inb,
                      const unsigned short* __restrict__ wt,
                      const float* __restrict__ bias,
                      unsigned short* __restrict__ outb) {
    __shared__ __align__(16) unsigned short As[128 * 32];
    __shared__ __align__(16) unsigned short Bs[128 * 32];

    constexpr int nwg = (BB * T / 128) * 3;        // 1536 (MEL) / 192 (LL); %8==0
    int wg = blockIdx.x;
    wg = (wg & 7) * (nwg >> 3) + (wg >> 3);        // XCD-contiguous chunks
    const int mt = wg / 3;
    const int n0 = (wg - mt * 3) * 128;
    const int m0 = mt * 128;
    const int b  = m0 / T;
    const int t0 = m0 - b * T;

    const int tid  = threadIdx.x;
    const int lane = tid & 63;
    const int wv   = tid >> 6;
    const int wr   = wv >> 1;
    const int wc   = wv & 1;

    f32x4 acc[4][4] = {};

    for (int kk0 = 0; kk0 < KKT; kk0 += 32) {
        const int kseg = kk0 / CC;                 // 0..2, chunks never straddle taps
        const int c0   = kk0 - kseg * CC;
        #pragma unroll
        for (int j = 0; j < 2; ++j) {
            const int cidx = j * 256 + tid;        // 16B-chunk index in tile
            const int row  = cidx >> 2;
            const int gch  = (cidx & 3) ^ ((row ^ (row >> 2)) & 3);
            const unsigned short* ga = inb +
                (((size_t)b * (T + 2) + (t0 + row + kseg)) * CC + c0) + gch * 8;
            gld_lds16(ga, &As[(j * 256 + wv * 64) * 8]);
            const unsigned short* gb = wt + ((size_t)(n0 + row) * KKT + kk0) + gch * 8;
            gld_lds16(gb, &Bs[(j * 256 + wv * 64) * 8]);
        }
        __syncthreads();

        bf16x8 af[4], bfr[4];
        #pragma unroll
        for (int i = 0; i < 4; ++i) {
            const int ar = wr * 64 + i * 16 + (lane & 15);
            const int ca = (lane >> 4) ^ ((ar ^ (ar >> 2)) & 3);
            af[i]  = *reinterpret_cast<bf16x8*>(&As[ar * 32 + ca * 8]);
            const int bn = wc * 64 + i * 16 + (lane & 15);
            const int cb = (lane >> 4) ^ ((bn ^ (bn >> 2)) & 3);
            bfr[i] = *reinterpret_cast<bf16x8*>(&Bs[bn * 32 + cb * 8]);
        }
        #pragma unroll
        for (int i = 0; i < 4; ++i)
            #pragma unroll
            for (int jn = 0; jn < 4; ++jn)
                acc[i][jn] = __builtin_amdgcn_mfma_f32_16x16x32_bf16(
                    af[i], bfr[jn], acc[i][jn], 0, 0, 0);
        __syncthreads();
    }

    // epilogue: bias + ReLU -> bf16 padded out
    #pragma unroll
    for (int jn = 0; jn < 4; ++jn) {
        const int col = n0 + wc * 64 + jn * 16 + (lane & 15);
        const float bsv = bias[col];
        #pragma unroll
        for (int i = 0; i < 4; ++i) {
            #pragma unroll
            for (int r = 0; r < 4; ++r) {
                const int row = wr * 64 + i * 16 + (lane >> 4) * 4 + r;
                const int t = t0 + row;
                float v = acc[i][jn][r] + bsv;
                v = v > 0.f ? v : 0.f;
                outb[((size_t)b * (T + 2) + (t + 1)) * CC + col] = f2bf(v);
            }
        }
    }
}

// ---------------- LayerNorm over F=384 (one wave/row, bf16x2 loads) --------
// FL=true: fuse Linear(F->1): emit only the scalar, skip the row write.
template<int T, bool FL>
__global__ void ln_kernel(const unsigned short* __restrict__ in,
                          const float* __restrict__ g, const float* __restrict__ be,
                          unsigned short* __restrict__ out,
                          const float* __restrict__ wl, const float* __restrict__ bl,
                          float* __restrict__ op) {
    const int row = blockIdx.x;
    const int b = row / T, t = row - b * T;
    const unsigned int* p =
        (const unsigned int*)(in + ((size_t)b * (T + 2) + t + 1) * CC);
    const int lane = threadIdx.x;
    float v[6], s = 0.f, s2 = 0.f;
    #pragma unroll
    for (int j = 0; j < 3; ++j) {
        const unsigned int u = p[j * 64 + lane];
        const float lo = bf2f((unsigned short)u);
        const float hi = bf2f((unsigned short)(u >> 16));
        v[2 * j] = lo; v[2 * j + 1] = hi;
        s += lo + hi; s2 += lo * lo + hi * hi;
    }
    #pragma unroll
    for (int off = 32; off; off >>= 1) {
        s  += __shfl_xor(s,  off);
        s2 += __shfl_xor(s2, off);
    }
    const float mu  = s * (1.f / 384.f);
    const float var = s2 * (1.f / 384.f) - mu * mu;
    const float rs  = rsqrtf(var + 1e-5f);
    if (FL) {
        float sl = 0.f;
        #pragma unroll
        for (int j = 0; j < 3; ++j) {
            const int f = (j * 64 + lane) * 2;
            const float2 gg = *(const float2*)(g  + f);
            const float2 bb = *(const float2*)(be + f);
            const float2 ww = *(const float2*)(wl + f);
            sl += ((v[2*j]   - mu) * rs * gg.x + bb.x) * ww.x;
            sl += ((v[2*j+1] - mu) * rs * gg.y + bb.y) * ww.y;
        }
        #pragma unroll
        for (int off = 32; off; off >>= 1) sl += __shfl_xor(sl, off);
        if (lane == 0) op[row] = sl + bl[0];
    } else {
        unsigned int* q = (unsigned int*)(out + ((size_t)b * (T + 2) + t + 1) * CC);
        #pragma unroll
        for (int j = 0; j < 3; ++j) {
            const int f = (j * 64 + lane) * 2;
            const float2 gg = *(const float2*)(g  + f);
            const float2 bb = *(const float2*)(be + f);
            const unsigned int lo = f2bf((v[2*j]   - mu) * rs * gg.x + bb.x);
            const unsigned int hi = f2bf((v[2*j+1] - mu) * rs * gg.y + bb.y);
            q[j * 64 + lane] = lo | (hi << 16);
        }
    }
}

// ---------------- cumsum of dur per batch ----------------------------------
__global__ void cumsum_kernel(const int* __restrict__ dur, int* __restrict__ cum) {
    __shared__ int s[LL];
    const int b = blockIdx.x, t = threadIdx.x;
    s[t] = dur[b * LL + t];
    __syncthreads();
    for (int off = 1; off < LL; off <<= 1) {
        int v = (t >= off) ? s[t - off] : 0;
        __syncthreads();
        s[t] += v;
        __syncthreads();
    }
    cum[b * LL + t] = s[t];
}

// ---------------- frame -> phoneme index (binary search), -1 if masked -----
__global__ void idx_kernel(const int* __restrict__ cum, int* __restrict__ idxm) {
    const int i = blockIdx.x * 256 + threadIdx.x;
    if (i >= BB * MEL) return;
    const int b = i / MEL, t = i - b * MEL;
    const int* cb = cum + b * LL;
    const int total = cb[LL - 1];
    int lo = 0, hi = LL;
    while (lo < hi) {
        const int mid = (lo + hi) >> 1;
        if (cb[mid] <= t) lo = mid + 1; else hi = mid;
    }
    int id = lo > LL - 1 ? LL - 1 : lo;
    idxm[i] = (t < total) ? id : -1;
}

// ---------------- gather: expanded fp32 -> d_out, bf16 padded -> bb0 -------
__global__ void gather_kernel(const float* __restrict__ x, const int* __restrict__ idxm,
                              float* __restrict__ out0, unsigned short* __restrict__ bb0) {
    const int row = blockIdx.x;
    const int b = row / MEL, t = row - b * MEL;
    const int f = threadIdx.x;
    const int id = idxm[row];
    const float v = (id >= 0) ? x[((size_t)b * LL + id) * CC + f] : 0.f;
    out0[(size_t)row * CC + f] = v;
    bb0[((size_t)b * (MEL + 2) + t + 1) * CC + f] = f2bf(v);
}

// ---------------- out += scalar(row); also produce bf16 padded copy --------
__global__ void addp_kernel(const float* __restrict__ pv, float* __restrict__ out0,
                            unsigned short* __restrict__ bb0) {
    const int row = blockIdx.x;
    const int b = row / MEL, t = row - b * MEL;
    const int f = threadIdx.x;
    const float pval = pv[row];
    const size_t o = (size_t)row * CC + f;
    const float v = out0[o] + pval;
    out0[o] = v;
    bb0[((size_t)b * (MEL + 2) + t + 1) * CC + f] = f2bf(v);
}

__global__ void adde_kernel(const float* __restrict__ ev, float* __restrict__ out0) {
    const int row = blockIdx.x;
    const int f = threadIdx.x;
    const size_t o = (size_t)row * CC + f;
    out0[o] = out0[o] + ev[row];
}

extern "C" void kernel_launch(void* const* d_in, const int* in_sizes, int n_in,
                              void* d_out, int out_size, void* d_ws, size_t ws_size,
                              hipStream_t stream) {
    const float* x = (const float*)d_in[0];
    const float* P[30];
    for (int i = 0; i < 30; ++i) P[i] = (const float*)d_in[1 + i];
    const int* dur = (const int*)d_in[31];
    float* out = (float*)d_out;

    char* ws = (char*)d_ws;
    const size_t WTT_ELEMS = (size_t)FF * KKT;            // 442368
    const size_t WTT_BYTES = WTT_ELEMS * 2;               // 884736
    unsigned short* wtt[6];
    for (int i = 0; i < 6; ++i) wtt[i] = (unsigned short*)(ws + i * WTT_BYTES);
    int* cum  = (int*)(ws + 5308416);
    int* idxm = (int*)(ws + 5341184);
    unsigned short* sb0 = (unsigned short*)(ws + 5603328);
    unsigned short* sb1 = sb0 + (size_t)BB * (LL + 2) * CC;
    unsigned short* sb2 = sb1 + (size_t)BB * (LL + 2) * CC;
    unsigned short* bb0 = (unsigned short*)(ws + 24551424);
    unsigned short* bb1 = bb0 + (size_t)BB * (MEL + 2) * CC;
    unsigned short* bb2 = bb1 + (size_t)BB * (MEL + 2) * CC;
    const size_t need = 24551424 + 3 * (size_t)BB * (MEL + 2) * CC * 2;
    if (ws_size < need)
        fprintf(stderr, "kernel_launch: ws too small: %zu < %zu\n", ws_size, need);

    const float *dp_w1=P[0], *dp_b1=P[1], *dp_g1=P[2], *dp_be1=P[3], *dp_w2=P[4],
                *dp_b2=P[5], *dp_g2=P[6], *dp_be2=P[7], *dp_wl=P[8], *dp_bl=P[9];
    const float *pp_w1=P[10], *pp_b1=P[11], *pp_g1=P[12], *pp_be1=P[13], *pp_w2=P[14],
                *pp_b2=P[15], *pp_g2=P[16], *pp_be2=P[17], *pp_wl=P[18], *pp_bl=P[19];
    const float *ep_w1=P[20], *ep_b1=P[21], *ep_g1=P[22], *ep_be1=P[23], *ep_w2=P[24],
                *ep_b2=P[25], *ep_g2=P[26], *ep_be2=P[27], *ep_wl=P[28], *ep_bl=P[29];

    const int wtg = (int)((WTT_ELEMS + 255) / 256);
    wtrans_kernel<<<wtg, 256, 0, stream>>>(dp_w1, wtt[0]);
    wtrans_kernel<<<wtg, 256, 0, stream>>>(dp_w2, wtt[1]);
    wtrans_kernel<<<wtg, 256, 0, stream>>>(pp_w1, wtt[2]);
    wtrans_kernel<<<wtg, 256, 0, stream>>>(pp_w2, wtt[3]);
    wtrans_kernel<<<wtg, 256, 0, stream>>>(ep_w1, wtt[4]);
    wtrans_kernel<<<wtg, 256, 0, stream>>>(ep_w2, wtt[5]);

    convert_x_kernel<<<(BB * LL * CC + 255) / 256, 256, 0, stream>>>(x, sb0);
    zpad_kernel<<<BB * 2, CC, 0, stream>>>(sb0, LL);
    zpad_kernel<<<BB * 2, CC, 0, stream>>>(sb2, LL);

    // duration predictor (T=512)
    {
        const int g = (BB * LL / 128) * 3;
        conv_gemm_kernel<LL><<<g, 256, 0, stream>>>(sb0, wtt[0], dp_b1, sb1);
        ln_kernel<LL, false><<<BB * LL, 64, 0, stream>>>(sb1, dp_g1, dp_be1, sb2,
                                                         nullptr, nullptr, nullptr);
        conv_gemm_kernel<LL><<<g, 256, 0, stream>>>(sb2, wtt[1], dp_b2, sb1);
        ln_kernel<LL, true><<<BB * LL, 64, 0, stream>>>(sb1, dp_g2, dp_be2, nullptr,
                                                        dp_wl, dp_bl, out + O_DUR);
    }

    // length regulate
    cumsum_kernel<<<BB, LL, 0, stream>>>(dur, cum);
    idx_kernel<<<(BB * MEL + 255) / 256, 256, 0, stream>>>(cum, idxm);
    zpad_kernel<<<BB * 2, CC, 0, stream>>>(bb0, MEL);
    zpad_kernel<<<BB * 2, CC, 0, stream>>>(bb2, MEL);
    gather_kernel<<<BB * MEL, CC, 0, stream>>>(x, idxm, out + O_OUT, bb0);

    // pitch predictor (T=4096) on expanded
    {
        const int g = (BB * MEL / 128) * 3;
        conv_gemm_kernel<MEL><<<g, 256, 0, stream>>>(bb0, wtt[2], pp_b1, bb1);
        ln_kernel<MEL, false><<<BB * MEL, 64, 0, stream>>>(bb1, pp_g1, pp_be1, bb2,
                                                           nullptr, nullptr, nullptr);
        conv_gemm_kernel<MEL><<<g, 256, 0, stream>>>(bb2, wtt[3], pp_b2, bb1);
        ln_kernel<MEL, true><<<BB * MEL, 64, 0, stream>>>(bb1, pp_g2, pp_be2, nullptr,
                                                          pp_wl, pp_bl, out + O_PIT);
    }

    // out = expanded + pitches (and bf16 copy for energy predictor)
    addp_kernel<<<BB * MEL, CC, 0, stream>>>(out + O_PIT, out + O_OUT, bb0);

    // energy predictor (T=4096) on out
    {
        const int g = (BB * MEL / 128) * 3;
        conv_gemm_kernel<MEL><<<g, 256, 0, stream>>>(bb0, wtt[4], ep_b1, bb1);
        ln_kernel<MEL, false><<<BB * MEL, 64, 0, stream>>>(bb1, ep_g1, ep_be1, bb2,
                                                           nullptr, nullptr, nullptr);
        conv_gemm_kernel<MEL><<<g, 256, 0, stream>>>(bb2, wtt[5], ep_b2, bb1);
        ln_kernel<MEL, true><<<BB * MEL, 64, 0, stream>>>(bb1, ep_g2, ep_be2, nullptr,
                                                          ep_wl, ep_bl, out + O_EN);
    }

    // out += energies
    adde_kernel<<<BB * MEL, CC, 0, stream>>>(out + O_EN, out + O_OUT);
}

// Round 3
// 474.010 us; speedup vs baseline: 1.5413x; 1.3601x over previous
//
#include <hip/hip_runtime.h>
#include <stdint.h>
#include <stdio.h>

#define BB   16
#define LL   512
#define CC   384
#define FF   384
#define KW   3
#define MEL  4096
#define KKT  (CC*KW)   // 1152

// output section offsets (fp32 elements)
#define O_OUT 0
#define N_OUT (BB*MEL*CC)          // 25165824
#define O_DUR (N_OUT)
#define O_PIT (O_DUR + BB*LL)
#define O_EN  (O_PIT + BB*MEL)

using bf16x8 = __attribute__((ext_vector_type(8))) short;
using f32x4  = __attribute__((ext_vector_type(4))) float;

__device__ __forceinline__ unsigned short f2bf(float v) {
    union { float f; unsigned int u; } cv; cv.f = v;
    unsigned int u = cv.u;
    u += 0x7FFFu + ((u >> 16) & 1u);   // RNE
    return (unsigned short)(u >> 16);
}
__device__ __forceinline__ float bf2f(unsigned short u) {
    union { unsigned int u; float f; } cv; cv.u = ((unsigned int)u) << 16; return cv.f;
}

__device__ __forceinline__ void gld_lds16(const unsigned short* gp, unsigned short* lp) {
    __builtin_amdgcn_global_load_lds(
        (const __attribute__((address_space(1))) unsigned int*)gp,
        (__attribute__((address_space(3))) unsigned int*)lp, 16, 0, 0);
}

// ---------------- weight transform: w[F][C][K] fp32 -> wt[F][k*C+c] bf16 ----
__global__ void wtrans_kernel(const float* __restrict__ w, unsigned short* __restrict__ wt) {
    int i = blockIdx.x * 256 + threadIdx.x;
    if (i >= FF * KKT) return;
    int f = i / KKT;
    int r = i - f * KKT;
    int k = r / CC;
    int c = r - k * CC;
    wt[i] = f2bf(w[(size_t)f * KKT + c * KW + k]);
}

// ---------------- x fp32 -> padded bf16 [B][L+2][C] ------------------------
__global__ void convert_x_kernel(const float* __restrict__ x, unsigned short* __restrict__ o) {
    int i = blockIdx.x * 256 + threadIdx.x;
    if (i >= BB * LL * CC) return;
    int b = i / (LL * CC);
    int r = i - b * (LL * CC);
    int t = r / CC;
    int c = r - t * CC;
    o[((size_t)b * (LL + 2) + t + 1) * CC + c] = f2bf(x[i]);
}

// ---------------- zero the two pad rows per batch --------------------------
__global__ void zpad_kernel(unsigned short* __restrict__ buf, int T) {
    int b = blockIdx.x >> 1;
    int w = blockIdx.x & 1;
    size_t row = (size_t)b * (T + 2) + (w ? (T + 1) : 0);
    buf[row * CC + threadIdx.x] = 0;
}

// ---------------- fused Conv(K=3)+bias+ReLU+LN [+Linear] -------------------
// Tile M=128 x N=384(all F). 512 thr, 8 waves (2M x 4N), per-wave 64x96.
// Double-buffered global_load_lds staging, counted vmcnt(4), raw barriers.
// FL=false: writes LN output (bf16, padded). FL=true: writes only Linear scalar.
template<int T, bool FL>
__global__ __launch_bounds__(512)
void conv_ln_kernel(const unsigned short* __restrict__ inb,
                    const unsigned short* __restrict__ wt,
                    const float* __restrict__ bias,
                    const float* __restrict__ g,
                    const float* __restrict__ be,
                    unsigned short* __restrict__ outb,
                    const float* __restrict__ wl,
                    const float* __restrict__ bl,
                    float* __restrict__ op) {
    // per buffer: A 128x32 (4096 shorts) + B 384x32 (12288 shorts) = 32KB
    __shared__ __align__(16) unsigned short LDS[2][16384];

    constexpr int NT = KKT / 32;   // 36
    const int m0 = blockIdx.x * 128;
    const int b  = m0 / T;
    const int t0 = m0 - b * T;
    const int tid  = threadIdx.x;
    const int lane = tid & 63;
    const int wv   = tid >> 6;
    const int wr   = wv >> 2;          // 0..1 -> 64 rows
    const int wc   = wv & 3;           // 0..3 -> 96 cols

    // staging sources (A: 1 chunk/thread, B: 3 chunks/thread); swizzle in source
    const int rowA = tid >> 2;
    const int gchA = (tid & 3) ^ ((rowA ^ (rowA >> 2)) & 3);
    const unsigned short* srcA =
        inb + ((size_t)b * (T + 2) + t0 + rowA) * CC + gchA * 8;
    const unsigned short* srcB0, *srcB1, *srcB2;
    {
        int cidx = tid;            int rB = cidx >> 2;
        srcB0 = wt + (size_t)rB * KKT + (((cidx & 3) ^ ((rB ^ (rB >> 2)) & 3)) * 8);
        cidx = 512 + tid;          rB = cidx >> 2;
        srcB1 = wt + (size_t)rB * KKT + (((cidx & 3) ^ ((rB ^ (rB >> 2)) & 3)) * 8);
        cidx = 1024 + tid;         rB = cidx >> 2;
        srcB2 = wt + (size_t)rB * KKT + (((cidx & 3) ^ ((rB ^ (rB >> 2)) & 3)) * 8);
    }

    f32x4 acc[4][6] = {};

    auto stage = [&](int bi, int t) {
        const int off = t * 32;    // A addr advances 32 shorts/K-step (384=12*32)
        gld_lds16(srcA + off, &LDS[bi][wv * 512]);
        gld_lds16(srcB0 + off, &LDS[bi][4096 + 0 * 4096 + wv * 512]);
        gld_lds16(srcB1 + off, &LDS[bi][4096 + 1 * 4096 + wv * 512]);
        gld_lds16(srcB2 + off, &LDS[bi][4096 + 2 * 4096 + wv * 512]);
    };

    auto compute = [&](int bi) {
        bf16x8 af[4], bf[6];
        #pragma unroll
        for (int i = 0; i < 4; ++i) {
            const int ar = wr * 64 + i * 16 + (lane & 15);
            const int ca = (lane >> 4) ^ ((ar ^ (ar >> 2)) & 3);
            af[i] = *reinterpret_cast<const bf16x8*>(&LDS[bi][ar * 32 + ca * 8]);
        }
        #pragma unroll
        for (int j = 0; j < 6; ++j) {
            const int bn = wc * 96 + j * 16 + (lane & 15);
            const int cb = (lane >> 4) ^ ((bn ^ (bn >> 2)) & 3);
            bf[j] = *reinterpret_cast<const bf16x8*>(&LDS[bi][4096 + bn * 32 + cb * 8]);
        }
        __builtin_amdgcn_s_setprio(1);
        #pragma unroll
        for (int i = 0; i < 4; ++i)
            #pragma unroll
            for (int j = 0; j < 6; ++j)
                acc[i][j] = __builtin_amdgcn_mfma_f32_16x16x32_bf16(
                    af[i], bf[j], acc[i][j], 0, 0, 0);
        __builtin_amdgcn_s_setprio(0);
    };

    stage(0, 0);
    int cur = 0;
    for (int t = 0; t < NT - 1; ++t) {
        stage(cur ^ 1, t + 1);
        asm volatile("s_waitcnt vmcnt(4)" ::: "memory");   // t's 4 loads done
        __builtin_amdgcn_s_barrier();
        asm volatile("" ::: "memory");
        compute(cur);
        __builtin_amdgcn_s_barrier();                      // all reads done before overwrite
        cur ^= 1;
    }
    asm volatile("s_waitcnt vmcnt(0)" ::: "memory");
    __builtin_amdgcn_s_barrier();
    asm volatile("" ::: "memory");
    compute(cur);
    __syncthreads();

    // ---------------- epilogue: bias + ReLU + LN [+ Linear] ----------------
    const int colb = wc * 96 + (lane & 15);
    float b6[6];
    #pragma unroll
    for (int j = 0; j < 6; ++j) b6[j] = bias[colb + j * 16];
    #pragma unroll
    for (int i = 0; i < 4; ++i)
        #pragma unroll
        for (int j = 0; j < 6; ++j)
            #pragma unroll
            for (int r = 0; r < 4; ++r) {
                float v = acc[i][j][r] + b6[j];
                acc[i][j][r] = v > 0.f ? v : 0.f;
            }

    // per-row partial sums (16-lane groups share a row)
    float S1[4][4], S2[4][4];
    #pragma unroll
    for (int i = 0; i < 4; ++i)
        #pragma unroll
        for (int r = 0; r < 4; ++r) {
            float s = 0.f, s2 = 0.f;
            #pragma unroll
            for (int j = 0; j < 6; ++j) { const float v = acc[i][j][r]; s += v; s2 += v * v; }
            #pragma unroll
            for (int m = 1; m <= 8; m <<= 1) { s += __shfl_xor(s, m); s2 += __shfl_xor(s2, m); }
            S1[i][r] = s; S2[i][r] = s2;
        }

    float2* red = (float2*)&LDS[0][0];     // 128 rows x 4 col-waves
    if ((lane & 15) == 0) {
        const int q = lane >> 4;
        #pragma unroll
        for (int i = 0; i < 4; ++i)
            #pragma unroll
            for (int r = 0; r < 4; ++r)
                red[(wr * 64 + i * 16 + q * 4 + r) * 4 + wc] = make_float2(S1[i][r], S2[i][r]);
    }
    __syncthreads();

    float g6[6], be6[6];
    #pragma unroll
    for (int j = 0; j < 6; ++j) { g6[j] = g[colb + j * 16]; be6[j] = be[colb + j * 16]; }

    if (!FL) {
        #pragma unroll
        for (int i = 0; i < 4; ++i)
            #pragma unroll
            for (int r = 0; r < 4; ++r) {
                const int row = wr * 64 + i * 16 + (lane >> 4) * 4 + r;
                const float2 p0 = red[row * 4 + 0], p1 = red[row * 4 + 1];
                const float2 p2 = red[row * 4 + 2], p3 = red[row * 4 + 3];
                const float S = p0.x + p1.x + p2.x + p3.x;
                const float Q = p0.y + p1.y + p2.y + p3.y;
                const float mu = S * (1.f / 384.f);
                const float rs = rsqrtf(Q * (1.f / 384.f) - mu * mu + 1e-5f);
                unsigned short* qp = outb + ((size_t)b * (T + 2) + t0 + row + 1) * CC + colb;
                #pragma unroll
                for (int j = 0; j < 6; ++j)
                    qp[j * 16] = f2bf((acc[i][j][r] - mu) * rs * g6[j] + be6[j]);
            }
    } else {
        float wl6[6];
        #pragma unroll
        for (int j = 0; j < 6; ++j) wl6[j] = wl[colb + j * 16];
        float* redl = (float*)&LDS[1][0];
        #pragma unroll
        for (int i = 0; i < 4; ++i)
            #pragma unroll
            for (int r = 0; r < 4; ++r) {
                const int row = wr * 64 + i * 16 + (lane >> 4) * 4 + r;
                const float2 p0 = red[row * 4 + 0], p1 = red[row * 4 + 1];
                const float2 p2 = red[row * 4 + 2], p3 = red[row * 4 + 3];
                const float S = p0.x + p1.x + p2.x + p3.x;
                const float Q = p0.y + p1.y + p2.y + p3.y;
                const float mu = S * (1.f / 384.f);
                const float rs = rsqrtf(Q * (1.f / 384.f) - mu * mu + 1e-5f);
                float sl = 0.f;
                #pragma unroll
                for (int j = 0; j < 6; ++j)
                    sl += ((acc[i][j][r] - mu) * rs * g6[j] + be6[j]) * wl6[j];
                #pragma unroll
                for (int m = 1; m <= 8; m <<= 1) sl += __shfl_xor(sl, m);
                if ((lane & 15) == 0) redl[row * 4 + wc] = sl;
            }
        __syncthreads();
        if (tid < 128)
            op[m0 + tid] = redl[tid * 4] + redl[tid * 4 + 1] +
                           redl[tid * 4 + 2] + redl[tid * 4 + 3] + bl[0];
    }
}

// ---------------- cumsum of dur per batch ----------------------------------
__global__ void cumsum_kernel(const int* __restrict__ dur, int* __restrict__ cum) {
    __shared__ int s[LL];
    const int b = blockIdx.x, t = threadIdx.x;
    s[t] = dur[b * LL + t];
    __syncthreads();
    for (int off = 1; off < LL; off <<= 1) {
        int v = (t >= off) ? s[t - off] : 0;
        __syncthreads();
        s[t] += v;
        __syncthreads();
    }
    cum[b * LL + t] = s[t];
}

// ---------------- frame -> phoneme index (binary search), -1 if masked -----
__global__ void idx_kernel(const int* __restrict__ cum, int* __restrict__ idxm) {
    const int i = blockIdx.x * 256 + threadIdx.x;
    if (i >= BB * MEL) return;
    const int b = i / MEL, t = i - b * MEL;
    const int* cb = cum + b * LL;
    const int total = cb[LL - 1];
    int lo = 0, hi = LL;
    while (lo < hi) {
        const int mid = (lo + hi) >> 1;
        if (cb[mid] <= t) lo = mid + 1; else hi = mid;
    }
    int id = lo > LL - 1 ? LL - 1 : lo;
    idxm[i] = (t < total) ? id : -1;
}

// ---------------- gather: x fp32 -> expanded bf16 padded (bb0) -------------
__global__ void gather_kernel(const float* __restrict__ x, const int* __restrict__ idxm,
                              unsigned short* __restrict__ bb0) {
    const int i = blockIdx.x * 256 + threadIdx.x;   // i < BB*MEL*96
    const int row = i / 96;
    const int c4  = (i - row * 96) * 4;
    const int b = row >> 12, t = row & (MEL - 1);
    const int id = idxm[row];
    float4 v = make_float4(0.f, 0.f, 0.f, 0.f);
    if (id >= 0) v = *(const float4*)(x + ((size_t)b * LL + id) * CC + c4);
    uint2 pk;
    pk.x = (unsigned int)f2bf(v.x) | ((unsigned int)f2bf(v.y) << 16);
    pk.y = (unsigned int)f2bf(v.z) | ((unsigned int)f2bf(v.w) << 16);
    *(uint2*)(bb0 + ((size_t)b * (MEL + 2) + t + 1) * CC + c4) = pk;
}

// ---------------- be0 = bf16(bb0 + pv[row]) (energy conv input) ------------
__global__ void addp_kernel(const unsigned short* __restrict__ bb0,
                            const float* __restrict__ pv,
                            unsigned short* __restrict__ be0) {
    const int i = blockIdx.x * 256 + threadIdx.x;   // i < BB*MEL*48
    const int row = i / 48;
    const int c8  = (i - row * 48) * 8;
    const int b = row >> 12, t = row & (MEL - 1);
    const float p = pv[row];
    const size_t o = ((size_t)b * (MEL + 2) + t + 1) * CC + c8;
    const uint4 in = *(const uint4*)(bb0 + o);
    uint4 ot;
    const unsigned int w[4] = {in.x, in.y, in.z, in.w};
    unsigned int r[4];
    #pragma unroll
    for (int k = 0; k < 4; ++k) {
        const float lo = bf2f((unsigned short)w[k]) + p;
        const float hi = bf2f((unsigned short)(w[k] >> 16)) + p;
        r[k] = (unsigned int)f2bf(lo) | ((unsigned int)f2bf(hi) << 16);
    }
    ot.x = r[0]; ot.y = r[1]; ot.z = r[2]; ot.w = r[3];
    *(uint4*)(be0 + o) = ot;
}

// ---------------- out0 = x[idx] (fp32 exact) + pv + ev ---------------------
__global__ void final_kernel(const float* __restrict__ x, const int* __restrict__ idxm,
                             const float* __restrict__ pv, const float* __restrict__ ev,
                             float* __restrict__ out0) {
    const int i = blockIdx.x * 256 + threadIdx.x;   // i < BB*MEL*96
    const int row = i / 96;
    const int c4  = (i - row * 96) * 4;
    const int b = row >> 12;
    const int id = idxm[row];
    const float add = pv[row] + ev[row];
    float4 v = make_float4(0.f, 0.f, 0.f, 0.f);
    if (id >= 0) v = *(const float4*)(x + ((size_t)b * LL + id) * CC + c4);
    v.x += add; v.y += add; v.z += add; v.w += add;
    *(float4*)(out0 + (size_t)row * CC + c4) = v;
}

extern "C" void kernel_launch(void* const* d_in, const int* in_sizes, int n_in,
                              void* d_out, int out_size, void* d_ws, size_t ws_size,
                              hipStream_t stream) {
    const float* x = (const float*)d_in[0];
    const float* P[30];
    for (int i = 0; i < 30; ++i) P[i] = (const float*)d_in[1 + i];
    const int* dur = (const int*)d_in[31];
    float* out = (float*)d_out;

    char* ws = (char*)d_ws;
    const size_t WTT_ELEMS = (size_t)FF * KKT;            // 442368
    const size_t WTT_BYTES = WTT_ELEMS * 2;               // 884736
    unsigned short* wtt[6];
    for (int i = 0; i < 6; ++i) wtt[i] = (unsigned short*)(ws + i * WTT_BYTES);
    int* cum  = (int*)(ws + 5308416);
    int* idxm = (int*)(ws + 5341184);
    unsigned short* sb0 = (unsigned short*)(ws + 5603328);                 // [16][514][384]
    unsigned short* h1s = (unsigned short*)(ws + 11919360);                // [16][514][384]
    unsigned short* bb0 = (unsigned short*)(ws + 18235392);                // [16][4098][384]
    unsigned short* h1p = (unsigned short*)(ws + 68616192);                // [16][4098][384]
    unsigned short* be0 = (unsigned short*)(ws + 118996992);               // [16][4098][384]
    const size_t need = 169377792;
    if (ws_size < need)
        fprintf(stderr, "kernel_launch: ws too small: %zu < %zu\n", ws_size, need);

    const float *dp_w1=P[0], *dp_b1=P[1], *dp_g1=P[2], *dp_be1=P[3], *dp_w2=P[4],
                *dp_b2=P[5], *dp_g2=P[6], *dp_be2=P[7], *dp_wl=P[8], *dp_bl=P[9];
    const float *pp_w1=P[10], *pp_b1=P[11], *pp_g1=P[12], *pp_be1=P[13], *pp_w2=P[14],
                *pp_b2=P[15], *pp_g2=P[16], *pp_be2=P[17], *pp_wl=P[18], *pp_bl=P[19];
    const float *ep_w1=P[20], *ep_b1=P[21], *ep_g1=P[22], *ep_be1=P[23], *ep_w2=P[24],
                *ep_b2=P[25], *ep_g2=P[26], *ep_be2=P[27], *ep_wl=P[28], *ep_bl=P[29];

    const int wtg = (int)((WTT_ELEMS + 255) / 256);
    wtrans_kernel<<<wtg, 256, 0, stream>>>(dp_w1, wtt[0]);
    wtrans_kernel<<<wtg, 256, 0, stream>>>(dp_w2, wtt[1]);
    wtrans_kernel<<<wtg, 256, 0, stream>>>(pp_w1, wtt[2]);
    wtrans_kernel<<<wtg, 256, 0, stream>>>(pp_w2, wtt[3]);
    wtrans_kernel<<<wtg, 256, 0, stream>>>(ep_w1, wtt[4]);
    wtrans_kernel<<<wtg, 256, 0, stream>>>(ep_w2, wtt[5]);

    convert_x_kernel<<<(BB * LL * CC + 255) / 256, 256, 0, stream>>>(x, sb0);
    zpad_kernel<<<BB * 2, CC, 0, stream>>>(sb0, LL);
    zpad_kernel<<<BB * 2, CC, 0, stream>>>(h1s, LL);
    zpad_kernel<<<BB * 2, CC, 0, stream>>>(bb0, MEL);
    zpad_kernel<<<BB * 2, CC, 0, stream>>>(h1p, MEL);
    zpad_kernel<<<BB * 2, CC, 0, stream>>>(be0, MEL);

    cumsum_kernel<<<BB, LL, 0, stream>>>(dur, cum);
    idx_kernel<<<(BB * MEL + 255) / 256, 256, 0, stream>>>(cum, idxm);

    // duration predictor (T=512)
    conv_ln_kernel<LL, false><<<BB * LL / 128, 512, 0, stream>>>(
        sb0, wtt[0], dp_b1, dp_g1, dp_be1, h1s, nullptr, nullptr, nullptr);
    conv_ln_kernel<LL, true><<<BB * LL / 128, 512, 0, stream>>>(
        h1s, wtt[1], dp_b2, dp_g2, dp_be2, nullptr, dp_wl, dp_bl, out + O_DUR);

    // length regulate -> bb0 (bf16 padded)
    gather_kernel<<<BB * MEL * 96 / 256, 256, 0, stream>>>(x, idxm, bb0);

    // pitch predictor (T=4096)
    conv_ln_kernel<MEL, false><<<BB * MEL / 128, 512, 0, stream>>>(
        bb0, wtt[2], pp_b1, pp_g1, pp_be1, h1p, nullptr, nullptr, nullptr);
    conv_ln_kernel<MEL, true><<<BB * MEL / 128, 512, 0, stream>>>(
        h1p, wtt[3], pp_b2, pp_g2, pp_be2, nullptr, pp_wl, pp_bl, out + O_PIT);

    // energy input = bf16(expanded + pitches)
    addp_kernel<<<BB * MEL * 48 / 256, 256, 0, stream>>>(bb0, out + O_PIT, be0);

    // energy predictor (T=4096)
    conv_ln_kernel<MEL, false><<<BB * MEL / 128, 512, 0, stream>>>(
        be0, wtt[4], ep_b1, ep_g1, ep_be1, h1p, nullptr, nullptr, nullptr);
    conv_ln_kernel<MEL, true><<<BB * MEL / 128, 512, 0, stream>>>(
        h1p, wtt[5], ep_b2, ep_g2, ep_be2, nullptr, ep_wl, ep_bl, out + O_EN);

    // final: out = expanded(exact fp32) + pitches + energies
    final_kernel<<<BB * MEL * 96 / 256, 256, 0, stream>>>(
        x, idxm, out + O_PIT, out + O_EN, out + O_OUT);
}

// Round 4
// 423.975 us; speedup vs baseline: 1.7232x; 1.1180x over previous
//
#include <hip/hip_runtime.h>
#include <stdint.h>
#include <stdio.h>

#define BB   16
#define LL   512
#define CC   384
#define FF   384
#define KW   3
#define MEL  4096
#define KKT  (CC*KW)   // 1152

// output section offsets (fp32 elements)
#define O_OUT 0
#define N_OUT (BB*MEL*CC)          // 25165824
#define O_DUR (N_OUT)
#define O_PIT (O_DUR + BB*LL)
#define O_EN  (O_PIT + BB*MEL)

using bf16x8 = __attribute__((ext_vector_type(8))) short;
using f32x4  = __attribute__((ext_vector_type(4))) float;

__device__ __forceinline__ unsigned short f2bf(float v) {
    union { float f; unsigned int u; } cv; cv.f = v;
    unsigned int u = cv.u;
    u += 0x7FFFu + ((u >> 16) & 1u);   // RNE
    return (unsigned short)(u >> 16);
}
__device__ __forceinline__ float bf2f(unsigned short u) {
    union { unsigned int u; float f; } cv; cv.u = ((unsigned int)u) << 16; return cv.f;
}

__device__ __forceinline__ void gld_lds16(const unsigned short* gp, unsigned short* lp) {
    __builtin_amdgcn_global_load_lds(
        (const __attribute__((address_space(1))) unsigned int*)gp,
        (__attribute__((address_space(3))) unsigned int*)lp, 16, 0, 0);
}

// ---------------- weight transform: w[F][C][K] fp32 -> wt[F][k*C+c] bf16 ----
__global__ void wtrans_kernel(const float* __restrict__ w, unsigned short* __restrict__ wt) {
    int i = blockIdx.x * 256 + threadIdx.x;
    if (i >= FF * KKT) return;
    int f = i / KKT;
    int r = i - f * KKT;
    int k = r / CC;
    int c = r - k * CC;
    wt[i] = f2bf(w[(size_t)f * KKT + c * KW + k]);
}

// ---------------- x fp32 -> padded bf16 [B][L+2][C] ------------------------
__global__ void convert_x_kernel(const float* __restrict__ x, unsigned short* __restrict__ o) {
    int i = blockIdx.x * 256 + threadIdx.x;
    if (i >= BB * LL * CC) return;
    int b = i / (LL * CC);
    int r = i - b * (LL * CC);
    int t = r / CC;
    int c = r - t * CC;
    o[((size_t)b * (LL + 2) + t + 1) * CC + c] = f2bf(x[i]);
}

// ---------------- zero the two pad rows per batch --------------------------
__global__ void zpad_kernel(unsigned short* __restrict__ buf, int T) {
    int b = blockIdx.x >> 1;
    int w = blockIdx.x & 1;
    size_t row = (size_t)b * (T + 2) + (w ? (T + 1) : 0);
    buf[row * CC + threadIdx.x] = 0;
}

// ---------------- fused Conv(K=3)+bias+ReLU+LN [+Linear] -------------------
// Tile M=128 x N=384(all F). 512 thr, 8 waves (2M x 4N), per-wave 64x96.
// 4-buffer circular LDS, depth-3 prefetch, counted vmcnt(8), 1 barrier/step.
template<int T, bool FL>
__global__ __launch_bounds__(512)
void conv_ln_kernel(const unsigned short* __restrict__ inb,
                    const unsigned short* __restrict__ wt,
                    const float* __restrict__ bias,
                    const float* __restrict__ g,
                    const float* __restrict__ be,
                    unsigned short* __restrict__ outb,
                    const float* __restrict__ wl,
                    const float* __restrict__ bl,
                    float* __restrict__ op) {
    // per buffer: A 128x32 (4096 shorts, 8KB) + B 384x32 (12288 shorts, 24KB)
    __shared__ __align__(16) unsigned short LDS[4][16384];

    constexpr int NT = KKT / 32;   // 36
    const int m0 = blockIdx.x * 128;
    const int b  = m0 / T;
    const int t0 = m0 - b * T;
    const int tid  = threadIdx.x;
    const int lane = tid & 63;
    const int wv   = tid >> 6;
    const int wr   = wv >> 2;          // 0..1 -> 64 rows
    const int wc   = wv & 3;           // 0..3 -> 96 cols

    // staging sources (A: 1 chunk/thread, B: 3 chunks/thread); swizzle in source
    const int rowA = tid >> 2;
    const int gchA = (tid & 3) ^ ((rowA ^ (rowA >> 2)) & 3);
    const unsigned short* srcA =
        inb + ((size_t)b * (T + 2) + t0 + rowA) * CC + gchA * 8;
    const unsigned short* srcB0, *srcB1, *srcB2;
    {
        int cidx = tid;            int rB = cidx >> 2;
        srcB0 = wt + (size_t)rB * KKT + (((cidx & 3) ^ ((rB ^ (rB >> 2)) & 3)) * 8);
        cidx = 512 + tid;          rB = cidx >> 2;
        srcB1 = wt + (size_t)rB * KKT + (((cidx & 3) ^ ((rB ^ (rB >> 2)) & 3)) * 8);
        cidx = 1024 + tid;         rB = cidx >> 2;
        srcB2 = wt + (size_t)rB * KKT + (((cidx & 3) ^ ((rB ^ (rB >> 2)) & 3)) * 8);
    }

    f32x4 acc[4][6] = {};

    auto stage = [&](int bi, int t) {
        const int off = t * 32;    // A addr advances 32 shorts/K-step (384=12*32)
        gld_lds16(srcA  + off, &LDS[bi][wv * 512]);
        gld_lds16(srcB0 + off, &LDS[bi][4096 + 0 * 4096 + wv * 512]);
        gld_lds16(srcB1 + off, &LDS[bi][4096 + 1 * 4096 + wv * 512]);
        gld_lds16(srcB2 + off, &LDS[bi][4096 + 2 * 4096 + wv * 512]);
    };

    auto compute = [&](int bi) {
        bf16x8 af[4], bf[6];
        #pragma unroll
        for (int i = 0; i < 4; ++i) {
            const int ar = wr * 64 + i * 16 + (lane & 15);
            const int ca = (lane >> 4) ^ ((ar ^ (ar >> 2)) & 3);
            af[i] = *reinterpret_cast<const bf16x8*>(&LDS[bi][ar * 32 + ca * 8]);
        }
        #pragma unroll
        for (int j = 0; j < 6; ++j) {
            const int bn = wc * 96 + j * 16 + (lane & 15);
            const int cb = (lane >> 4) ^ ((bn ^ (bn >> 2)) & 3);
            bf[j] = *reinterpret_cast<const bf16x8*>(&LDS[bi][4096 + bn * 32 + cb * 8]);
        }
        __builtin_amdgcn_s_setprio(1);
        #pragma unroll
        for (int i = 0; i < 4; ++i)
            #pragma unroll
            for (int j = 0; j < 6; ++j)
                acc[i][j] = __builtin_amdgcn_mfma_f32_16x16x32_bf16(
                    af[i], bf[j], acc[i][j], 0, 0, 0);
        __builtin_amdgcn_s_setprio(0);
    };

    // depth-3 prologue
    stage(0, 0);
    stage(1, 1);
    stage(2, 2);

    #pragma unroll 4
    for (int t = 0; t < NT; ++t) {
        // my stage for tile t (issued 3 steps ago) has landed when <=8 remain
        asm volatile("s_waitcnt vmcnt(8)" ::: "memory");
        __builtin_amdgcn_s_barrier();     // everyone's tile-t loads landed;
        asm volatile("" ::: "memory");    // everyone's t-1 reads consumed
        int nt_ = t + 3; if (nt_ > NT - 1) nt_ = NT - 1;   // clamped dup-stage tail
        stage((t + 3) & 3, nt_);
        asm volatile("" ::: "memory");
        compute(t & 3);
    }
    asm volatile("s_waitcnt vmcnt(0)" ::: "memory");  // drain dup stages
    __syncthreads();

    // ---------------- epilogue: bias + ReLU + LN [+ Linear] ----------------
    const int colb = wc * 96 + (lane & 15);
    float b6[6];
    #pragma unroll
    for (int j = 0; j < 6; ++j) b6[j] = bias[colb + j * 16];
    #pragma unroll
    for (int i = 0; i < 4; ++i)
        #pragma unroll
        for (int j = 0; j < 6; ++j)
            #pragma unroll
            for (int r = 0; r < 4; ++r) {
                float v = acc[i][j][r] + b6[j];
                acc[i][j][r] = v > 0.f ? v : 0.f;
            }

    // per-row partial sums (16-lane groups share a row)
    float S1[4][4], S2[4][4];
    #pragma unroll
    for (int i = 0; i < 4; ++i)
        #pragma unroll
        for (int r = 0; r < 4; ++r) {
            float s = 0.f, s2 = 0.f;
            #pragma unroll
            for (int j = 0; j < 6; ++j) { const float v = acc[i][j][r]; s += v; s2 += v * v; }
            #pragma unroll
            for (int m = 1; m <= 8; m <<= 1) { s += __shfl_xor(s, m); s2 += __shfl_xor(s2, m); }
            S1[i][r] = s; S2[i][r] = s2;
        }

    float2* red = (float2*)&LDS[0][0];     // 128 rows x 4 col-waves
    if ((lane & 15) == 0) {
        const int q = lane >> 4;
        #pragma unroll
        for (int i = 0; i < 4; ++i)
            #pragma unroll
            for (int r = 0; r < 4; ++r)
                red[(wr * 64 + i * 16 + q * 4 + r) * 4 + wc] = make_float2(S1[i][r], S2[i][r]);
    }
    __syncthreads();

    float g6[6], be6[6];
    #pragma unroll
    for (int j = 0; j < 6; ++j) { g6[j] = g[colb + j * 16]; be6[j] = be[colb + j * 16]; }

    if (!FL) {
        #pragma unroll
        for (int i = 0; i < 4; ++i)
            #pragma unroll
            for (int r = 0; r < 4; ++r) {
                const int row = wr * 64 + i * 16 + (lane >> 4) * 4 + r;
                const float2 p0 = red[row * 4 + 0], p1 = red[row * 4 + 1];
                const float2 p2 = red[row * 4 + 2], p3 = red[row * 4 + 3];
                const float S = p0.x + p1.x + p2.x + p3.x;
                const float Q = p0.y + p1.y + p2.y + p3.y;
                const float mu = S * (1.f / 384.f);
                const float rs = rsqrtf(Q * (1.f / 384.f) - mu * mu + 1e-5f);
                unsigned short* qp = outb + ((size_t)b * (T + 2) + t0 + row + 1) * CC + colb;
                #pragma unroll
                for (int j = 0; j < 6; ++j)
                    qp[j * 16] = f2bf((acc[i][j][r] - mu) * rs * g6[j] + be6[j]);
            }
    } else {
        float wl6[6];
        #pragma unroll
        for (int j = 0; j < 6; ++j) wl6[j] = wl[colb + j * 16];
        float* redl = (float*)&LDS[1][0];
        #pragma unroll
        for (int i = 0; i < 4; ++i)
            #pragma unroll
            for (int r = 0; r < 4; ++r) {
                const int row = wr * 64 + i * 16 + (lane >> 4) * 4 + r;
                const float2 p0 = red[row * 4 + 0], p1 = red[row * 4 + 1];
                const float2 p2 = red[row * 4 + 2], p3 = red[row * 4 + 3];
                const float S = p0.x + p1.x + p2.x + p3.x;
                const float Q = p0.y + p1.y + p2.y + p3.y;
                const float mu = S * (1.f / 384.f);
                const float rs = rsqrtf(Q * (1.f / 384.f) - mu * mu + 1e-5f);
                float sl = 0.f;
                #pragma unroll
                for (int j = 0; j < 6; ++j)
                    sl += ((acc[i][j][r] - mu) * rs * g6[j] + be6[j]) * wl6[j];
                #pragma unroll
                for (int m = 1; m <= 8; m <<= 1) sl += __shfl_xor(sl, m);
                if ((lane & 15) == 0) redl[row * 4 + wc] = sl;
            }
        __syncthreads();
        if (tid < 128)
            op[m0 + tid] = redl[tid * 4] + redl[tid * 4 + 1] +
                           redl[tid * 4 + 2] + redl[tid * 4 + 3] + bl[0];
    }
}

// ---------------- cumsum of dur per batch ----------------------------------
__global__ void cumsum_kernel(const int* __restrict__ dur, int* __restrict__ cum) {
    __shared__ int s[LL];
    const int b = blockIdx.x, t = threadIdx.x;
    s[t] = dur[b * LL + t];
    __syncthreads();
    for (int off = 1; off < LL; off <<= 1) {
        int v = (t >= off) ? s[t - off] : 0;
        __syncthreads();
        s[t] += v;
        __syncthreads();
    }
    cum[b * LL + t] = s[t];
}

// ---------------- frame -> phoneme index (binary search), -1 if masked -----
__global__ void idx_kernel(const int* __restrict__ cum, int* __restrict__ idxm) {
    const int i = blockIdx.x * 256 + threadIdx.x;
    if (i >= BB * MEL) return;
    const int b = i / MEL, t = i - b * MEL;
    const int* cb = cum + b * LL;
    const int total = cb[LL - 1];
    int lo = 0, hi = LL;
    while (lo < hi) {
        const int mid = (lo + hi) >> 1;
        if (cb[mid] <= t) lo = mid + 1; else hi = mid;
    }
    int id = lo > LL - 1 ? LL - 1 : lo;
    idxm[i] = (t < total) ? id : -1;
}

// ---------------- gather: x fp32 -> expanded bf16 padded (bb0) -------------
__global__ void gather_kernel(const float* __restrict__ x, const int* __restrict__ idxm,
                              unsigned short* __restrict__ bb0) {
    const int i = blockIdx.x * 256 + threadIdx.x;   // i < BB*MEL*96
    const int row = i / 96;
    const int c4  = (i - row * 96) * 4;
    const int b = row >> 12, t = row & (MEL - 1);
    const int id = idxm[row];
    float4 v = make_float4(0.f, 0.f, 0.f, 0.f);
    if (id >= 0) v = *(const float4*)(x + ((size_t)b * LL + id) * CC + c4);
    uint2 pk;
    pk.x = (unsigned int)f2bf(v.x) | ((unsigned int)f2bf(v.y) << 16);
    pk.y = (unsigned int)f2bf(v.z) | ((unsigned int)f2bf(v.w) << 16);
    *(uint2*)(bb0 + ((size_t)b * (MEL + 2) + t + 1) * CC + c4) = pk;
}

// ---------------- be0 = bf16(bb0 + pv[row]) (energy conv input) ------------
__global__ void addp_kernel(const unsigned short* __restrict__ bb0,
                            const float* __restrict__ pv,
                            unsigned short* __restrict__ be0) {
    const int i = blockIdx.x * 256 + threadIdx.x;   // i < BB*MEL*48
    const int row = i / 48;
    const int c8  = (i - row * 48) * 8;
    const int b = row >> 12, t = row & (MEL - 1);
    const float p = pv[row];
    const size_t o = ((size_t)b * (MEL + 2) + t + 1) * CC + c8;
    const uint4 in = *(const uint4*)(bb0 + o);
    uint4 ot;
    const unsigned int w[4] = {in.x, in.y, in.z, in.w};
    unsigned int r[4];
    #pragma unroll
    for (int k = 0; k < 4; ++k) {
        const float lo = bf2f((unsigned short)w[k]) + p;
        const float hi = bf2f((unsigned short)(w[k] >> 16)) + p;
        r[k] = (unsigned int)f2bf(lo) | ((unsigned int)f2bf(hi) << 16);
    }
    ot.x = r[0]; ot.y = r[1]; ot.z = r[2]; ot.w = r[3];
    *(uint4*)(be0 + o) = ot;
}

// ---------------- out0 = x[idx] (fp32 exact) + pv + ev ---------------------
__global__ void final_kernel(const float* __restrict__ x, const int* __restrict__ idxm,
                             const float* __restrict__ pv, const float* __restrict__ ev,
                             float* __restrict__ out0) {
    const int i = blockIdx.x * 256 + threadIdx.x;   // i < BB*MEL*96
    const int row = i / 96;
    const int c4  = (i - row * 96) * 4;
    const int b = row >> 12;
    const int id = idxm[row];
    const float add = pv[row] + ev[row];
    float4 v = make_float4(0.f, 0.f, 0.f, 0.f);
    if (id >= 0) v = *(const float4*)(x + ((size_t)b * LL + id) * CC + c4);
    v.x += add; v.y += add; v.z += add; v.w += add;
    *(float4*)(out0 + (size_t)row * CC + c4) = v;
}

extern "C" void kernel_launch(void* const* d_in, const int* in_sizes, int n_in,
                              void* d_out, int out_size, void* d_ws, size_t ws_size,
                              hipStream_t stream) {
    const float* x = (const float*)d_in[0];
    const float* P[30];
    for (int i = 0; i < 30; ++i) P[i] = (const float*)d_in[1 + i];
    const int* dur = (const int*)d_in[31];
    float* out = (float*)d_out;

    char* ws = (char*)d_ws;
    const size_t WTT_ELEMS = (size_t)FF * KKT;            // 442368
    const size_t WTT_BYTES = WTT_ELEMS * 2;               // 884736
    unsigned short* wtt[6];
    for (int i = 0; i < 6; ++i) wtt[i] = (unsigned short*)(ws + i * WTT_BYTES);
    int* cum  = (int*)(ws + 5308416);
    int* idxm = (int*)(ws + 5341184);
    unsigned short* sb0 = (unsigned short*)(ws + 5603328);                 // [16][514][384]
    unsigned short* h1s = (unsigned short*)(ws + 11919360);                // [16][514][384]
    unsigned short* bb0 = (unsigned short*)(ws + 18235392);                // [16][4098][384]
    unsigned short* h1p = (unsigned short*)(ws + 68616192);                // [16][4098][384]
    unsigned short* be0 = (unsigned short*)(ws + 118996992);               // [16][4098][384]
    const size_t need = 169377792;
    if (ws_size < need)
        fprintf(stderr, "kernel_launch: ws too small: %zu < %zu\n", ws_size, need);

    const float *dp_w1=P[0], *dp_b1=P[1], *dp_g1=P[2], *dp_be1=P[3], *dp_w2=P[4],
                *dp_b2=P[5], *dp_g2=P[6], *dp_be2=P[7], *dp_wl=P[8], *dp_bl=P[9];
    const float *pp_w1=P[10], *pp_b1=P[11], *pp_g1=P[12], *pp_be1=P[13], *pp_w2=P[14],
                *pp_b2=P[15], *pp_g2=P[16], *pp_be2=P[17], *pp_wl=P[18], *pp_bl=P[19];
    const float *ep_w1=P[20], *ep_b1=P[21], *ep_g1=P[22], *ep_be1=P[23], *ep_w2=P[24],
                *ep_b2=P[25], *ep_g2=P[26], *ep_be2=P[27], *ep_wl=P[28], *ep_bl=P[29];

    const int wtg = (int)((WTT_ELEMS + 255) / 256);
    wtrans_kernel<<<wtg, 256, 0, stream>>>(dp_w1, wtt[0]);
    wtrans_kernel<<<wtg, 256, 0, stream>>>(dp_w2, wtt[1]);
    wtrans_kernel<<<wtg, 256, 0, stream>>>(pp_w1, wtt[2]);
    wtrans_kernel<<<wtg, 256, 0, stream>>>(pp_w2, wtt[3]);
    wtrans_kernel<<<wtg, 256, 0, stream>>>(ep_w1, wtt[4]);
    wtrans_kernel<<<wtg, 256, 0, stream>>>(ep_w2, wtt[5]);

    convert_x_kernel<<<(BB * LL * CC + 255) / 256, 256, 0, stream>>>(x, sb0);
    zpad_kernel<<<BB * 2, CC, 0, stream>>>(sb0, LL);
    zpad_kernel<<<BB * 2, CC, 0, stream>>>(h1s, LL);
    zpad_kernel<<<BB * 2, CC, 0, stream>>>(bb0, MEL);
    zpad_kernel<<<BB * 2, CC, 0, stream>>>(h1p, MEL);
    zpad_kernel<<<BB * 2, CC, 0, stream>>>(be0, MEL);

    cumsum_kernel<<<BB, LL, 0, stream>>>(dur, cum);
    idx_kernel<<<(BB * MEL + 255) / 256, 256, 0, stream>>>(cum, idxm);

    // duration predictor (T=512)
    conv_ln_kernel<LL, false><<<BB * LL / 128, 512, 0, stream>>>(
        sb0, wtt[0], dp_b1, dp_g1, dp_be1, h1s, nullptr, nullptr, nullptr);
    conv_ln_kernel<LL, true><<<BB * LL / 128, 512, 0, stream>>>(
        h1s, wtt[1], dp_b2, dp_g2, dp_be2, nullptr, dp_wl, dp_bl, out + O_DUR);

    // length regulate -> bb0 (bf16 padded)
    gather_kernel<<<BB * MEL * 96 / 256, 256, 0, stream>>>(x, idxm, bb0);

    // pitch predictor (T=4096)
    conv_ln_kernel<MEL, false><<<BB * MEL / 128, 512, 0, stream>>>(
        bb0, wtt[2], pp_b1, pp_g1, pp_be1, h1p, nullptr, nullptr, nullptr);
    conv_ln_kernel<MEL, true><<<BB * MEL / 128, 512, 0, stream>>>(
        h1p, wtt[3], pp_b2, pp_g2, pp_be2, nullptr, pp_wl, pp_bl, out + O_PIT);

    // energy input = bf16(expanded + pitches)
    addp_kernel<<<BB * MEL * 48 / 256, 256, 0, stream>>>(bb0, out + O_PIT, be0);

    // energy predictor (T=4096)
    conv_ln_kernel<MEL, false><<<BB * MEL / 128, 512, 0, stream>>>(
        be0, wtt[4], ep_b1, ep_g1, ep_be1, h1p, nullptr, nullptr, nullptr);
    conv_ln_kernel<MEL, true><<<BB * MEL / 128, 512, 0, stream>>>(
        h1p, wtt[5], ep_b2, ep_g2, ep_be2, nullptr, ep_wl, ep_bl, out + O_EN);

    // final: out = expanded(exact fp32) + pitches + energies
    final_kernel<<<BB * MEL * 96 / 256, 256, 0, stream>>>(
        x, idxm, out + O_PIT, out + O_EN, out + O_OUT);
}